// Round 6
// baseline (484.842 us; speedup 1.0000x reference)
//
#include <hip/hip_runtime.h>
#include <math.h>

typedef short s16x8 __attribute__((ext_vector_type(8)));
typedef float f32x4 __attribute__((ext_vector_type(4)));

__device__ __forceinline__ float lrelu(float x, float s) { return x > 0.0f ? x : s * x; }

// RNE f32 -> bf16 (bit-level)
__device__ __forceinline__ unsigned short f2bf(float f) {
  unsigned int u = __float_as_uint(f);
  u = (u + 0x7FFFu + ((u >> 16) & 1u)) >> 16;
  return (unsigned short)u;
}
__device__ __forceinline__ float bf2f(unsigned short h) {
  return __uint_as_float(((unsigned int)h) << 16);
}

// async global->LDS, 16B per lane; LDS dest is wave-uniform base + lane*16
__device__ __forceinline__ void gload_lds16(void* lds, const void* g) {
  __builtin_amdgcn_global_load_lds(
      (const __attribute__((address_space(1))) unsigned int*)g,
      (__attribute__((address_space(3))) unsigned int*)lds, 16, 0, 0);
}

// ======================== CSR build ========================
__global__ void deg_kernel(const int* __restrict__ dst, int* __restrict__ deg, int E) {
  int e = blockIdx.x * blockDim.x + threadIdx.x;
  if (e < E) atomicAdd(&deg[dst[e]], 1);
}

// --- device-wide exclusive scan of deg[N], 3 tiny kernels ---
__global__ __launch_bounds__(256) void bsum_kernel(const int* __restrict__ deg,
                                                   int* __restrict__ bsum, int N) {
  int t = blockIdx.x * 256 + threadIdx.x;
  int v = (t < N) ? deg[t] : 0;
  #pragma unroll
  for (int off = 1; off < 64; off <<= 1) v += __shfl_xor(v, off, 64);
  __shared__ int ws[4];
  if ((threadIdx.x & 63) == 0) ws[threadIdx.x >> 6] = v;
  __syncthreads();
  if (threadIdx.x == 0) bsum[blockIdx.x] = ws[0] + ws[1] + ws[2] + ws[3];
}

__global__ __launch_bounds__(256) void bscan_kernel(const int* __restrict__ bsum,
                                                    int* __restrict__ boff, int nb,
                                                    int* __restrict__ rowptr_total) {
  __shared__ int s[256];
  int t = threadIdx.x;
  int v = (t < nb) ? bsum[t] : 0;
  s[t] = v;
  __syncthreads();
  for (int off = 1; off < 256; off <<= 1) {
    int u = (t >= off) ? s[t - off] : 0;
    __syncthreads();
    s[t] += u;
    __syncthreads();
  }
  if (t < nb) boff[t] = s[t] - v;               // exclusive block offset
  if (t == nb - 1) *rowptr_total = s[t];        // rowptr[N] = E total
}

__global__ __launch_bounds__(256) void bwrite_kernel(const int* __restrict__ deg,
                                                     const int* __restrict__ boff,
                                                     int* __restrict__ rowptr,
                                                     int* __restrict__ cursor, int N) {
  __shared__ int s[256];
  int t = blockIdx.x * 256 + threadIdx.x;
  int v = (t < N) ? deg[t] : 0;
  s[threadIdx.x] = v;
  __syncthreads();
  for (int off = 1; off < 256; off <<= 1) {
    int u = (threadIdx.x >= off) ? s[threadIdx.x - off] : 0;
    __syncthreads();
    s[threadIdx.x] += u;
    __syncthreads();
  }
  if (t < N) {
    int ex = boff[blockIdx.x] + s[threadIdx.x] - v;   // exclusive prefix
    rowptr[t] = ex;
    cursor[t] = ex;
  }
}

__global__ void fill_kernel(const int* __restrict__ src, const int* __restrict__ dst,
                            int* __restrict__ cursor, int* __restrict__ colsrc, int E) {
  int e = blockIdx.x * blockDim.x + threadIdx.x;
  if (e < E) {
    int d = dst[e];
    int pos = atomicAdd(&cursor[d], 1);
    colsrc[pos] = src[e];
  }
}

// ======================== f32 -> bf16 conversions ========================
__global__ void cvt_rows_kernel(const float* __restrict__ src, unsigned short* __restrict__ dst,
                                int nrows, int prows) {
  int t = blockIdx.x * blockDim.x + threadIdx.x;
  int row = t >> 6;
  int c = (t & 63) * 4;
  if (row >= prows) return;
  float4 v = make_float4(0.f, 0.f, 0.f, 0.f);
  if (row < nrows) v = *(const float4*)&src[(size_t)row * 256 + c];
  ushort4 o;
  o.x = f2bf(v.x); o.y = f2bf(v.y); o.z = f2bf(v.z); o.w = f2bf(v.w);
  *(ushort4*)&dst[(size_t)row * 256 + c] = o;
}

__global__ void cvt_gT_kernel(const float* __restrict__ g, unsigned short* __restrict__ gT) {
  int idx = blockIdx.x * blockDim.x + threadIdx.x;  // 0..262143
  int k = idx >> 10, n = idx & 1023;
  gT[(size_t)n * 256 + k] = f2bf(g[idx]);
}

// ======================== bf16 MFMA GEMM, 128x128 tile, BK=64 ========================
// A: [Mp][256] bf16. B: [Ntot][256] bf16 (row = out col). 4 waves; wave w owns rows
// w*32..+31 x 128 cols. LDS 16B-chunk XOR-swizzled via pre-swizzled global src (rule 21).
// Flat 1-D grid with XCD-co-location: all NY sibling blocks (same m-tile xt, different
// j = kchunk/head) share id&7 -> same XCD under round-robin dispatch -> A panel is
// L2-resident after first sibling (T1 mechanism). Grid = ceil(gm/8)*8*NY, guard xt>=gm.
// EPI=0: store C bf16 [Mp][256]; AH>0: fused a_src/a_dst dot products.
//   AH==2: j == head, direct store. AH==1: atomicAdd partials (zeroed before).
// EPI=1: fused cosine epilogue, j == kchunk (col-tile of g == K-chunk of out3).
template<int EPI, int AH, int NY>
__global__ __launch_bounds__(256, 2) void gemm_bf16(
    const unsigned short* __restrict__ A, const unsigned short* __restrict__ B,
    unsigned short* __restrict__ Cb,
    const float* __restrict__ avs, const float* __restrict__ avd,
    float* __restrict__ asrcO, float* __restrict__ adstO,
    const float* __restrict__ mu, const float* __restrict__ nmu,
    float* __restrict__ outcos, int M)
{
  __shared__ unsigned short As[128 * 64];
  __shared__ unsigned short Bs[128 * 64];
  const int gm = (M + 127) >> 7;         // # m-tiles
  const int id = blockIdx.x;
  const int xcd = id & 7;
  const int tt = id >> 3;
  const int j  = tt & (NY - 1);          // sibling index (kchunk / head)
  const int xg = tt / NY;
  const int xt = xg * 8 + xcd;           // m-tile
  if (xt >= gm) return;
  const int t = threadIdx.x;
  const int w = t >> 6;
  const int l = t & 63;
  const int m0 = xt * 128;
  const int n0 = j * 128;

  f32x4 acc[2][8];
  #pragma unroll
  for (int i = 0; i < 2; ++i)
    #pragma unroll
    for (int jj = 0; jj < 8; ++jj) acc[i][jj] = (f32x4){0.f, 0.f, 0.f, 0.f};

  const unsigned char* Ab = (const unsigned char*)A;
  const unsigned char* Bb = (const unsigned char*)B;
  unsigned char* AsB = (unsigned char*)As;
  unsigned char* BsB = (unsigned char*)Bs;

  const int srow = l >> 3;               // 0..7: row within 8-row segment
  const int gchk = (l & 7) ^ srow;       // pre-swizzled global 16B-chunk index

  for (int kb = 0; kb < 256; kb += 64) {
    #pragma unroll
    for (int i = 0; i < 4; ++i) {
      int seg = w * 4 + i;               // 16 segments of 8 rows each
      int row = seg * 8 + srow;          // local row 0..127
      gload_lds16(AsB + seg * 1024,
                  Ab + (size_t)(m0 + row) * 512 + kb * 2 + gchk * 16);
      gload_lds16(BsB + seg * 1024,
                  Bb + (size_t)(n0 + row) * 512 + kb * 2 + gchk * 16);
    }
    asm volatile("s_waitcnt vmcnt(0)" ::: "memory");
    __syncthreads();

    const int rl = l & 15;
    const int kc = l >> 4;               // 0..3
    #pragma unroll
    for (int ks = 0; ks < 2; ++ks) {
      s16x8 af[2], bfr[8];
      #pragma unroll
      for (int mf = 0; mf < 2; ++mf) {
        int r = w * 32 + mf * 16 + rl;
        int slot = (ks * 4 + kc) ^ (r & 7);
        af[mf] = *(const s16x8*)&As[r * 64 + slot * 8];
      }
      #pragma unroll
      for (int nf = 0; nf < 8; ++nf) {
        int r = nf * 16 + rl;
        int slot = (ks * 4 + kc) ^ (r & 7);
        bfr[nf] = *(const s16x8*)&Bs[r * 64 + slot * 8];
      }
      #pragma unroll
      for (int mf = 0; mf < 2; ++mf)
        #pragma unroll
        for (int nf = 0; nf < 8; ++nf)
          acc[mf][nf] = __builtin_amdgcn_mfma_f32_16x16x32_bf16(af[mf], bfr[nf], acc[mf][nf], 0, 0, 0);
    }
    __syncthreads();
  }

  if (EPI == 0) {
    // C/D layout: col = lane&15, row = (lane>>4)*4 + reg  [m89/m91 verified]
    #pragma unroll
    for (int mf = 0; mf < 2; ++mf)
      #pragma unroll
      for (int nf = 0; nf < 8; ++nf)
        #pragma unroll
        for (int jj = 0; jj < 4; ++jj) {
          int r = m0 + w * 32 + mf * 16 + (l >> 4) * 4 + jj;
          int c = n0 + nf * 16 + (l & 15);
          Cb[(size_t)r * 256 + c] = f2bf(acc[mf][nf][jj]);
        }
    if (AH > 0) {
      float avS[8], avD[8];
      #pragma unroll
      for (int nf = 0; nf < 8; ++nf) {
        avS[nf] = avs[n0 + nf * 16 + (l & 15)];
        avD[nf] = avd[n0 + nf * 16 + (l & 15)];
      }
      #pragma unroll
      for (int mf = 0; mf < 2; ++mf)
        #pragma unroll
        for (int jj = 0; jj < 4; ++jj) {
          float ds = 0.f, dd = 0.f;
          #pragma unroll
          for (int nf = 0; nf < 8; ++nf) {
            float o = acc[mf][nf][jj];
            ds = fmaf(o, avS[nf], ds);
            dd = fmaf(o, avD[nf], dd);
          }
          #pragma unroll
          for (int off = 1; off < 16; off <<= 1) {
            ds += __shfl_xor(ds, off, 64);
            dd += __shfl_xor(dd, off, 64);
          }
          if ((l & 15) == 0) {
            int r = m0 + w * 32 + mf * 16 + (l >> 4) * 4 + jj;
            if (r < M) {
              if (AH == 2) {
                asrcO[(size_t)r * 2 + j] = ds;
                adstO[(size_t)r * 2 + j] = dd;
              } else {
                atomicAdd(&asrcO[r], ds);
                atomicAdd(&adstO[r], dd);
              }
            }
          }
        }
    }
  } else {
    const int kchunk = j;                // 0..7
    float nm = nmu[kchunk];
    float mv[8];
    #pragma unroll
    for (int nf = 0; nf < 8; ++nf) mv[nf] = mu[kchunk * 128 + nf * 16 + (l & 15)];
    #pragma unroll
    for (int mf = 0; mf < 2; ++mf)
      #pragma unroll
      for (int jj = 0; jj < 4; ++jj) {
        float num = 0.f, ss = 0.f;
        #pragma unroll
        for (int nf = 0; nf < 8; ++nf) {
          float o = acc[mf][nf][jj];
          num = fmaf(o, mv[nf], num);
          ss  = fmaf(o, o, ss);
        }
        #pragma unroll
        for (int off = 1; off < 16; off <<= 1) {
          num += __shfl_xor(num, off, 64);
          ss  += __shfl_xor(ss, off, 64);
        }
        if ((l & 15) == 0) {
          int r = m0 + w * 32 + mf * 16 + (l >> 4) * 4 + jj;
          if (r < M) outcos[(size_t)r * 8 + kchunk] = num / fmaxf(sqrtf(ss) * nm, 1e-8f);
        }
      }
  }
}

// ======================== edge alpha (normalized attention weights) ========================
// One wave per node, lane-parallel chunked online softmax; pass 2 writes
// alpha = exp(e - m)/s per CSR slot (planar per head) + self weight per node.
template<int H>
__global__ __launch_bounds__(256) void alpha_edge_kernel(
    const float* __restrict__ asrc, const float* __restrict__ adst,
    const int* __restrict__ rowptr, const int* __restrict__ colsrc,
    float* __restrict__ al0, float* __restrict__ al1,
    float* __restrict__ asl0, float* __restrict__ asl1, int N)
{
  int wid = threadIdx.x >> 6, lane = threadIdx.x & 63;
  int n = blockIdx.x * 4 + wid;
  if (n >= N) return;
  int beg = rowptr[n], end = rowptr[n + 1];
  float ad0 = adst[(size_t)n * H + 0];
  float ad1 = (H == 2) ? adst[(size_t)n * 2 + 1] : 0.f;
  float self0 = lrelu(asrc[(size_t)n * H + 0] + ad0, 0.2f);
  float self1 = (H == 2) ? lrelu(asrc[(size_t)n * 2 + 1] + ad1, 0.2f) : 0.f;
  float m0 = self0, m1 = self1, s0 = 1.f, s1 = 1.f;

  for (int cbeg = beg; cbeg < end; cbeg += 64) {
    int cnt = end - cbeg; if (cnt > 64) cnt = 64;
    float e0 = -1e30f, e1 = -1e30f;
    if (lane < cnt) {
      int s = colsrc[cbeg + lane];
      if (H == 2) {
        float2 av = *(const float2*)&asrc[(size_t)s * 2];
        e0 = lrelu(av.x + ad0, 0.2f);
        e1 = lrelu(av.y + ad1, 0.2f);
      } else {
        e0 = lrelu(asrc[s] + ad0, 0.2f);
      }
    }
    float c0 = e0, c1 = e1;
    #pragma unroll
    for (int off = 32; off >= 1; off >>= 1) {
      c0 = fmaxf(c0, __shfl_xor(c0, off, 64));
      if (H == 2) c1 = fmaxf(c1, __shfl_xor(c1, off, 64));
    }
    float nm0 = fmaxf(m0, c0); s0 *= __expf(m0 - nm0); m0 = nm0;
    if (H == 2) { float nm1 = fmaxf(m1, c1); s1 *= __expf(m1 - nm1); m1 = nm1; }
    float p0 = (lane < cnt) ? __expf(e0 - m0) : 0.f;
    float p1 = (H == 2 && lane < cnt) ? __expf(e1 - m1) : 0.f;
    #pragma unroll
    for (int off = 32; off >= 1; off >>= 1) {
      p0 += __shfl_xor(p0, off, 64);
      if (H == 2) p1 += __shfl_xor(p1, off, 64);
    }
    s0 += p0; if (H == 2) s1 += p1;
  }

  float i0 = 1.f / s0;
  float i1 = (H == 2) ? 1.f / s1 : 0.f;
  if (lane == 0) {
    asl0[n] = __expf(self0 - m0) * i0;
    if (H == 2) asl1[n] = __expf(self1 - m1) * i1;
  }
  for (int cbeg = beg; cbeg < end; cbeg += 64) {
    int cnt = end - cbeg; if (cnt > 64) cnt = 64;
    if (lane < cnt) {
      int s = colsrc[cbeg + lane];
      if (H == 2) {
        float2 av = *(const float2*)&asrc[(size_t)s * 2];
        al0[cbeg + lane] = __expf(lrelu(av.x + ad0, 0.2f) - m0) * i0;
        al1[cbeg + lane] = __expf(lrelu(av.y + ad1, 0.2f) - m1) * i1;
      } else {
        al0[cbeg + lane] = __expf(lrelu(asrc[s] + ad0, 0.2f) - m0) * i0;
      }
    }
  }
}

// ======================== feature-split gather ========================
// Block = 4 nodes x one 64-feat group (= one 128B line per edge).
// Flat id: fg = (id&7)>>1  ->  all blocks on XCD k share one feature group
// (T1 mechanism): per-XCD L2 working set = N*128B = 6.4 MB (resident), HBM
// replication 8x -> 2x. Inner loop: wave-uniform readlane broadcasts of
// (src, alpha), SGPR-base 1-line loads, 8 in flight.
template<int H, bool OUT_LRELU>
__global__ __launch_bounds__(256) void gat_gather_kernel(
    const unsigned short* __restrict__ hin,
    const float* __restrict__ al0, const float* __restrict__ al1,
    const float* __restrict__ asl0, const float* __restrict__ asl1,
    const int* __restrict__ rowptr, const int* __restrict__ colsrc,
    const float* __restrict__ bias, unsigned short* __restrict__ outp, int N)
{
  const int id = blockIdx.x;
  const int fg = (id & 7) >> 1;            // feature group 0..3
  const int sub = id & 1;
  const int wid = threadIdx.x >> 6, lane = threadIdx.x & 63;
  const int n = (id >> 3) * 8 + sub * 4 + wid;
  if (n >= N) return;
  const int f = fg * 64 + lane;
  const float* alph = (H == 2 && fg >= 2) ? al1 : al0;
  const float* aslf = (H == 2 && fg >= 2) ? asl1 : asl0;
  int beg = rowptr[n], end = rowptr[n + 1];

  float acc = aslf[n] * bf2f(hin[(size_t)n * 256 + f]);

  for (int cbeg = beg; cbeg < end; cbeg += 64) {
    int cnt = end - cbeg; if (cnt > 64) cnt = 64;
    int sidx = 0; float aval = 0.f;
    if (lane < cnt) {
      sidx = colsrc[cbeg + lane];
      aval = alph[cbeg + lane];
    }
    int nr = (cnt + 7) & ~7;
    for (int u0 = 0; u0 < nr; u0 += 8) {
      int ss[8]; float aa[8];
      #pragma unroll
      for (int u = 0; u < 8; ++u) {
        ss[u] = __builtin_amdgcn_readlane(sidx, u0 + u);
        aa[u] = __uint_as_float(
            __builtin_amdgcn_readlane((int)__float_as_uint(aval), u0 + u));
      }
      float hv[8];
      #pragma unroll
      for (int u = 0; u < 8; ++u)
        hv[u] = bf2f(hin[(size_t)ss[u] * 256 + f]);
      #pragma unroll
      for (int u = 0; u < 8; ++u)
        acc = fmaf(hv[u], aa[u], acc);
    }
  }

  float v = acc + bias[f];
  if (OUT_LRELU) v = lrelu(v, 0.01f);
  outp[(size_t)n * 256 + f] = f2bf(v);
}

// ======================== mu norms ========================
__global__ __launch_bounds__(64) void munorm_kernel(const float* __restrict__ mu,
                                                    float* __restrict__ norm_mu) {
  int lane = threadIdx.x;
  for (int k = 0; k < 8; ++k) {
    float v0 = mu[k * 128 + lane];
    float v1 = mu[k * 128 + 64 + lane];
    float s = v0 * v0 + v1 * v1;
    #pragma unroll
    for (int off = 1; off < 64; off <<= 1) s += __shfl_xor(s, off, 64);
    if (lane == 0) norm_mu[k] = sqrtf(s);
  }
}

// ======================== launch ========================
extern "C" void kernel_launch(void* const* d_in, const int* in_sizes, int n_in,
                              void* d_out, int out_size, void* d_ws, size_t ws_size,
                              hipStream_t stream) {
  const float* x      = (const float*)d_in[0];
  const int*   ei     = (const int*)  d_in[1];
  const float* W1     = (const float*)d_in[2];
  const float* a_src1 = (const float*)d_in[3];
  const float* a_dst1 = (const float*)d_in[4];
  const float* b1     = (const float*)d_in[5];
  const float* W2     = (const float*)d_in[6];
  const float* a_src2 = (const float*)d_in[7];
  const float* a_dst2 = (const float*)d_in[8];
  const float* b2     = (const float*)d_in[9];
  const float* g      = (const float*)d_in[10];
  const float* mu     = (const float*)d_in[11];

  const int N  = in_sizes[0] / 256;            // 50000
  const int E  = in_sizes[1] / 2;              // 800000
  const int Mp = ((N + 127) / 128) * 128;      // 50048
  const int nb = (N + 255) / 256;              // 196 scan blocks
  const int* src = ei;
  const int* dst = ei + E;

  // ---- workspace layout ----
  unsigned short* us = (unsigned short*)d_ws;
  size_t off = 0;
  unsigned short* xb  = us + off; off += (size_t)Mp * 256;   // x bf16 (reused as out2b)
  unsigned short* h1b = us + off; off += (size_t)Mp * 256;
  unsigned short* o1b = us + off; off += (size_t)Mp * 256;
  unsigned short* h2b = us + off; off += (size_t)Mp * 256;
  unsigned short* o2b = xb;                                  // alias: xb dead after gemm1
  float* f = (float*)(us + off);
  size_t fo = 0;
  float* asrc1 = f + fo; fo += (size_t)N * 2;
  float* adst1 = f + fo; fo += (size_t)N * 2;
  float* asrc2 = f + fo; fo += N;
  float* adst2 = f + fo; fo += N;
  float* nmu   = f + fo; fo += 8;
  float* al10  = f + fo; fo += E;      // layer1 alpha head0
  float* al11  = f + fo; fo += E;      // layer1 alpha head1
  float* al2   = f + fo; fo += E;      // layer2 alpha
  float* as10  = f + fo; fo += N;      // layer1 self weight head0
  float* as11  = f + fo; fo += N;
  float* as2   = f + fo; fo += N;
  int* deg    = (int*)(f + fo);
  int* rowptr = deg + N;
  int* cursor = rowptr + N + 1;
  int* colsrc = cursor + N;
  int* bsum   = colsrc + E;          // nb
  int* boff   = bsum + 256;          // nb
  unsigned short* w1b = (unsigned short*)(boff + 256);
  unsigned short* w2b = w1b + 256 * 256;
  unsigned short* gTb = w2b + 256 * 256;

  // ---- CSR build ----
  hipMemsetAsync(deg, 0, (size_t)N * sizeof(int), stream);
  hipMemsetAsync(asrc2, 0, (size_t)N * 2 * sizeof(float), stream);  // asrc2+adst2 contiguous
  deg_kernel<<<(E + 255) / 256, 256, 0, stream>>>(dst, deg, E);
  bsum_kernel<<<nb, 256, 0, stream>>>(deg, bsum, N);
  bscan_kernel<<<1, 256, 0, stream>>>(bsum, boff, nb, rowptr + N);
  bwrite_kernel<<<nb, 256, 0, stream>>>(deg, boff, rowptr, cursor, N);
  fill_kernel<<<(E + 255) / 256, 256, 0, stream>>>(src, dst, cursor, colsrc, E);

  // ---- conversions ----
  cvt_rows_kernel<<<Mp / 4, 256, 0, stream>>>(x, xb, N, Mp);
  cvt_rows_kernel<<<64, 256, 0, stream>>>(W1, w1b, 256, 256);
  cvt_rows_kernel<<<64, 256, 0, stream>>>(W2, w2b, 256, 256);
  cvt_gT_kernel<<<1024, 256, 0, stream>>>(g, gTb);
  munorm_kernel<<<1, 64, 0, stream>>>(mu, nmu);

  const int gm  = Mp / 128;                  // 391 m-tiles
  const int nxg = (gm + 7) / 8;              // 49 XCD groups
  const int g2  = nxg * 8 * 2;               // flat grid, NY=2
  const int g8  = nxg * 8 * 8;               // flat grid, NY=8
  const int nbk = (N + 7) / 8;               // gather granules
  const int gg  = nbk * 8;                   // gather grid

  // ---- layer 1 (alpha fused into GEMM epilogue: j == head) ----
  gemm_bf16<0, 2, 2><<<g2, 256, 0, stream>>>(xb, w1b, h1b,
      a_src1, a_dst1, asrc1, adst1, nullptr, nullptr, nullptr, N);
  alpha_edge_kernel<2><<<(N + 3) / 4, 256, 0, stream>>>(
      asrc1, adst1, rowptr, colsrc, al10, al11, as10, as11, N);
  gat_gather_kernel<2, true><<<gg, 256, 0, stream>>>(
      h1b, al10, al11, as10, as11, rowptr, colsrc, b1, o1b, N);

  // ---- layer 2 (alpha partials via atomicAdd into zeroed asrc2/adst2) ----
  gemm_bf16<0, 1, 2><<<g2, 256, 0, stream>>>(o1b, w2b, h2b,
      a_src2, a_dst2, asrc2, adst2, nullptr, nullptr, nullptr, N);
  alpha_edge_kernel<1><<<(N + 3) / 4, 256, 0, stream>>>(
      asrc2, adst2, rowptr, colsrc, al2, al2, as2, as2, N);
  gat_gather_kernel<1, false><<<gg, 256, 0, stream>>>(
      h2b, al2, al2, as2, as2, rowptr, colsrc, b2, o2b, N);

  // ---- projection + fused cosine (j == kchunk) ----
  gemm_bf16<1, 0, 8><<<g8, 256, 0, stream>>>(o2b, gTb, nullptr,
      nullptr, nullptr, nullptr, nullptr, mu, nmu, (float*)d_out, N);
}

// Round 7
// 416.656 us; speedup vs baseline: 1.1637x; 1.1637x over previous
//
#include <hip/hip_runtime.h>
#include <math.h>

typedef short s16x8 __attribute__((ext_vector_type(8)));
typedef float f32x4 __attribute__((ext_vector_type(4)));

__device__ __forceinline__ float lrelu(float x, float s) { return x > 0.0f ? x : s * x; }

// RNE f32 -> bf16 (bit-level)
__device__ __forceinline__ unsigned short f2bf(float f) {
  unsigned int u = __float_as_uint(f);
  u = (u + 0x7FFFu + ((u >> 16) & 1u)) >> 16;
  return (unsigned short)u;
}
__device__ __forceinline__ float bf2f(unsigned short h) {
  return __uint_as_float(((unsigned int)h) << 16);
}
__device__ __forceinline__ float bcastf(float v, int l) {
  return __uint_as_float((unsigned)__builtin_amdgcn_readlane((int)__float_as_uint(v), l));
}

// async global->LDS, 16B per lane; LDS dest is wave-uniform base + lane*16
__device__ __forceinline__ void gload_lds16(void* lds, const void* g) {
  __builtin_amdgcn_global_load_lds(
      (const __attribute__((address_space(1))) unsigned int*)g,
      (__attribute__((address_space(3))) unsigned int*)lds, 16, 0, 0);
}

// ======================== CSR build ========================
__global__ void deg_kernel(const int* __restrict__ dst, int* __restrict__ deg, int E) {
  int e = blockIdx.x * blockDim.x + threadIdx.x;
  if (e < E) atomicAdd(&deg[dst[e]], 1);
}

// --- device-wide exclusive scan of deg[N], 3 tiny kernels ---
__global__ __launch_bounds__(256) void bsum_kernel(const int* __restrict__ deg,
                                                   int* __restrict__ bsum, int N) {
  int t = blockIdx.x * 256 + threadIdx.x;
  int v = (t < N) ? deg[t] : 0;
  #pragma unroll
  for (int off = 1; off < 64; off <<= 1) v += __shfl_xor(v, off, 64);
  __shared__ int ws[4];
  if ((threadIdx.x & 63) == 0) ws[threadIdx.x >> 6] = v;
  __syncthreads();
  if (threadIdx.x == 0) bsum[blockIdx.x] = ws[0] + ws[1] + ws[2] + ws[3];
}

__global__ __launch_bounds__(256) void bscan_kernel(const int* __restrict__ bsum,
                                                    int* __restrict__ boff, int nb,
                                                    int* __restrict__ rowptr_total) {
  __shared__ int s[256];
  int t = threadIdx.x;
  int v = (t < nb) ? bsum[t] : 0;
  s[t] = v;
  __syncthreads();
  for (int off = 1; off < 256; off <<= 1) {
    int u = (t >= off) ? s[t - off] : 0;
    __syncthreads();
    s[t] += u;
    __syncthreads();
  }
  if (t < nb) boff[t] = s[t] - v;               // exclusive block offset
  if (t == nb - 1) *rowptr_total = s[t];        // rowptr[N] = E total
}

__global__ __launch_bounds__(256) void bwrite_kernel(const int* __restrict__ deg,
                                                     const int* __restrict__ boff,
                                                     int* __restrict__ rowptr,
                                                     int* __restrict__ cursor, int N) {
  __shared__ int s[256];
  int t = blockIdx.x * 256 + threadIdx.x;
  int v = (t < N) ? deg[t] : 0;
  s[threadIdx.x] = v;
  __syncthreads();
  for (int off = 1; off < 256; off <<= 1) {
    int u = (threadIdx.x >= off) ? s[threadIdx.x - off] : 0;
    __syncthreads();
    s[threadIdx.x] += u;
    __syncthreads();
  }
  if (t < N) {
    int ex = boff[blockIdx.x] + s[threadIdx.x] - v;   // exclusive prefix
    rowptr[t] = ex;
    cursor[t] = ex;
  }
}

__global__ void fill_kernel(const int* __restrict__ src, const int* __restrict__ dst,
                            int* __restrict__ cursor, int* __restrict__ colsrc, int E) {
  int e = blockIdx.x * blockDim.x + threadIdx.x;
  if (e < E) {
    int d = dst[e];
    int pos = atomicAdd(&cursor[d], 1);
    colsrc[pos] = src[e];
  }
}

// ======================== f32 -> bf16 conversions ========================
__global__ void cvt_rows_kernel(const float* __restrict__ src, unsigned short* __restrict__ dst,
                                int nrows, int prows) {
  int t = blockIdx.x * blockDim.x + threadIdx.x;
  int row = t >> 6;
  int c = (t & 63) * 4;
  if (row >= prows) return;
  float4 v = make_float4(0.f, 0.f, 0.f, 0.f);
  if (row < nrows) v = *(const float4*)&src[(size_t)row * 256 + c];
  ushort4 o;
  o.x = f2bf(v.x); o.y = f2bf(v.y); o.z = f2bf(v.z); o.w = f2bf(v.w);
  *(ushort4*)&dst[(size_t)row * 256 + c] = o;
}

__global__ void cvt_gT_kernel(const float* __restrict__ g, unsigned short* __restrict__ gT) {
  int idx = blockIdx.x * blockDim.x + threadIdx.x;  // 0..262143
  int k = idx >> 10, n = idx & 1023;
  gT[(size_t)n * 256 + k] = f2bf(g[idx]);
}

// ======================== bf16 MFMA GEMM, 128x128 tile, BK=64 ========================
// A: [Mp][256] bf16. B: [Ntot][256] bf16 (row = out col). 4 waves; wave w owns rows
// w*32..+31 x 128 cols. LDS 16B-chunk XOR-swizzled via pre-swizzled global src (rule 21).
// EPI=0: store C bf16 [Mp][256]; AH>0: fused a_src/a_dst dot products.
//   AH==2: blockIdx.y == head, direct store. AH==1: atomicAdd partials (zeroed before).
// EPI=1: fused cosine epilogue (block col-tile == K-chunk of 128).
template<int EPI, int AH>
__global__ __launch_bounds__(256, 2) void gemm_bf16(
    const unsigned short* __restrict__ A, const unsigned short* __restrict__ B,
    unsigned short* __restrict__ Cb,
    const float* __restrict__ avs, const float* __restrict__ avd,
    float* __restrict__ asrcO, float* __restrict__ adstO,
    const float* __restrict__ mu, const float* __restrict__ nmu,
    float* __restrict__ outcos, int M)
{
  __shared__ unsigned short As[128 * 64];
  __shared__ unsigned short Bs[128 * 64];
  const int t = threadIdx.x;
  const int w = t >> 6;
  const int l = t & 63;
  const int m0 = blockIdx.x * 128;
  const int n0 = blockIdx.y * 128;

  f32x4 acc[2][8];
  #pragma unroll
  for (int i = 0; i < 2; ++i)
    #pragma unroll
    for (int j = 0; j < 8; ++j) acc[i][j] = (f32x4){0.f, 0.f, 0.f, 0.f};

  const unsigned char* Ab = (const unsigned char*)A;
  const unsigned char* Bb = (const unsigned char*)B;
  unsigned char* AsB = (unsigned char*)As;
  unsigned char* BsB = (unsigned char*)Bs;

  const int srow = l >> 3;               // 0..7: row within 8-row segment
  const int gchk = (l & 7) ^ srow;       // pre-swizzled global 16B-chunk index

  for (int kb = 0; kb < 256; kb += 64) {
    #pragma unroll
    for (int i = 0; i < 4; ++i) {
      int seg = w * 4 + i;               // 16 segments of 8 rows each
      int row = seg * 8 + srow;          // local row 0..127
      gload_lds16(AsB + seg * 1024,
                  Ab + (size_t)(m0 + row) * 512 + kb * 2 + gchk * 16);
      gload_lds16(BsB + seg * 1024,
                  Bb + (size_t)(n0 + row) * 512 + kb * 2 + gchk * 16);
    }
    asm volatile("s_waitcnt vmcnt(0)" ::: "memory");
    __syncthreads();

    const int rl = l & 15;
    const int kc = l >> 4;               // 0..3
    #pragma unroll
    for (int ks = 0; ks < 2; ++ks) {
      s16x8 af[2], bfr[8];
      #pragma unroll
      for (int mf = 0; mf < 2; ++mf) {
        int r = w * 32 + mf * 16 + rl;
        int slot = (ks * 4 + kc) ^ (r & 7);
        af[mf] = *(const s16x8*)&As[r * 64 + slot * 8];
      }
      #pragma unroll
      for (int nf = 0; nf < 8; ++nf) {
        int r = nf * 16 + rl;
        int slot = (ks * 4 + kc) ^ (r & 7);
        bfr[nf] = *(const s16x8*)&Bs[r * 64 + slot * 8];
      }
      #pragma unroll
      for (int mf = 0; mf < 2; ++mf)
        #pragma unroll
        for (int nf = 0; nf < 8; ++nf)
          acc[mf][nf] = __builtin_amdgcn_mfma_f32_16x16x32_bf16(af[mf], bfr[nf], acc[mf][nf], 0, 0, 0);
    }
    __syncthreads();
  }

  if (EPI == 0) {
    // C/D layout: col = lane&15, row = (lane>>4)*4 + reg  [m89/m91 verified]
    #pragma unroll
    for (int mf = 0; mf < 2; ++mf)
      #pragma unroll
      for (int nf = 0; nf < 8; ++nf)
        #pragma unroll
        for (int j = 0; j < 4; ++j) {
          int r = m0 + w * 32 + mf * 16 + (l >> 4) * 4 + j;
          int c = n0 + nf * 16 + (l & 15);
          Cb[(size_t)r * 256 + c] = f2bf(acc[mf][nf][j]);
        }
    if (AH > 0) {
      float avS[8], avD[8];
      #pragma unroll
      for (int nf = 0; nf < 8; ++nf) {
        avS[nf] = avs[n0 + nf * 16 + (l & 15)];
        avD[nf] = avd[n0 + nf * 16 + (l & 15)];
      }
      #pragma unroll
      for (int mf = 0; mf < 2; ++mf)
        #pragma unroll
        for (int j = 0; j < 4; ++j) {
          float ds = 0.f, dd = 0.f;
          #pragma unroll
          for (int nf = 0; nf < 8; ++nf) {
            float o = acc[mf][nf][j];
            ds = fmaf(o, avS[nf], ds);
            dd = fmaf(o, avD[nf], dd);
          }
          #pragma unroll
          for (int off = 1; off < 16; off <<= 1) {
            ds += __shfl_xor(ds, off, 64);
            dd += __shfl_xor(dd, off, 64);
          }
          if ((l & 15) == 0) {
            int r = m0 + w * 32 + mf * 16 + (l >> 4) * 4 + j;
            if (r < M) {
              if (AH == 2) {
                asrcO[(size_t)r * 2 + blockIdx.y] = ds;
                adstO[(size_t)r * 2 + blockIdx.y] = dd;
              } else {
                atomicAdd(&asrcO[r], ds);
                atomicAdd(&adstO[r], dd);
              }
            }
          }
        }
    }
  } else {
    const int kchunk = blockIdx.y;       // 0..7
    float nm = nmu[kchunk];
    float mv[8];
    #pragma unroll
    for (int nf = 0; nf < 8; ++nf) mv[nf] = mu[kchunk * 128 + nf * 16 + (l & 15)];
    #pragma unroll
    for (int mf = 0; mf < 2; ++mf)
      #pragma unroll
      for (int j = 0; j < 4; ++j) {
        float num = 0.f, ss = 0.f;
        #pragma unroll
        for (int nf = 0; nf < 8; ++nf) {
          float o = acc[mf][nf][j];
          num = fmaf(o, mv[nf], num);
          ss  = fmaf(o, o, ss);
        }
        #pragma unroll
        for (int off = 1; off < 16; off <<= 1) {
          num += __shfl_xor(num, off, 64);
          ss  += __shfl_xor(ss, off, 64);
        }
        if ((l & 15) == 0) {
          int r = m0 + w * 32 + mf * 16 + (l >> 4) * 4 + j;
          if (r < M) outcos[(size_t)r * 8 + kchunk] = num / fmaxf(sqrtf(ss) * nm, 1e-8f);
        }
      }
  }
}

// ======================== GAT aggregation ========================
// One wave per node; lane owns 4 feature cols (lane*4..+3). Lane-parallel chunked
// online softmax (64 edges/chunk). Gather: ONE edge per step across all 64 lanes
// (8B/lane = full 512B row); (src, alpha) broadcast via v_readlane into SGPRs ->
// SALU address math + SGPR-base loads with constant voffset (lane*8); unrolled x4
// => 4 row-loads in flight, no DS-pipe ops. No cross-lane merge at the end.
template<int H, bool OUT_LRELU>
__global__ __launch_bounds__(256) void agg_kernel(
    const unsigned short* __restrict__ hin, const float* __restrict__ asrc,
    const float* __restrict__ adst, const int* __restrict__ rowptr,
    const int* __restrict__ colsrc, const float* __restrict__ bias,
    unsigned short* __restrict__ outp, int N)
{
  int wid  = threadIdx.x >> 6;
  int lane = threadIdx.x & 63;
  int n = blockIdx.x * 4 + wid;
  if (n >= N) return;
  const int head = (H == 2) ? (lane >> 5) : 0;   // cols lane*4..+3 all in one head

  int beg = rowptr[n], end = rowptr[n + 1];

  float ad0 = adst[(size_t)n * H + 0];
  float ad1 = (H == 2) ? adst[(size_t)n * 2 + 1] : 0.f;
  float m0 = lrelu(asrc[(size_t)n * H + 0] + ad0, 0.2f);       // self-loop logit
  float m1 = (H == 2) ? lrelu(asrc[(size_t)n * 2 + 1] + ad1, 0.2f) : 0.f;
  float s0 = 1.f, s1 = 1.f;                        // exp(self - m) = 1

  float acc[4];
  {
    ushort4 hv = *(const ushort4*)&hin[(size_t)n * 256 + lane * 4];
    acc[0] = bf2f(hv.x); acc[1] = bf2f(hv.y);
    acc[2] = bf2f(hv.z); acc[3] = bf2f(hv.w);
  }

  for (int cbeg = beg; cbeg < end; cbeg += 64) {
    int cnt = end - cbeg; if (cnt > 64) cnt = 64;
    int src_i = 0;
    float e0 = -1e30f, e1 = -1e30f;
    if (lane < cnt) {
      src_i = colsrc[cbeg + lane];
      if (H == 2) {
        float2 av = *(const float2*)&asrc[(size_t)src_i * 2];
        e0 = lrelu(av.x + ad0, 0.2f);
        e1 = lrelu(av.y + ad1, 0.2f);
      } else {
        e0 = lrelu(asrc[src_i] + ad0, 0.2f);
      }
    }
    // chunk max
    float c0 = e0, c1 = e1;
    #pragma unroll
    for (int off = 32; off >= 1; off >>= 1) {
      c0 = fmaxf(c0, __shfl_xor(c0, off, 64));
      if (H == 2) c1 = fmaxf(c1, __shfl_xor(c1, off, 64));
    }
    float nm0 = fmaxf(m0, c0);
    float r0 = __expf(m0 - nm0); m0 = nm0;
    float r1 = 1.f;
    if (H == 2) { float nm1 = fmaxf(m1, c1); r1 = __expf(m1 - nm1); m1 = nm1; }
    s0 *= r0; if (H == 2) s1 *= r1;
    float rh = (H == 2 && head) ? r1 : r0;
    #pragma unroll
    for (int k = 0; k < 4; ++k) acc[k] *= rh;
    // per-edge p (0 for invalid lanes)
    float p0 = (lane < cnt) ? __expf(e0 - m0) : 0.f;
    float p1 = (H == 2 && lane < cnt) ? __expf(e1 - m1) : 0.f;
    float t0 = p0, t1 = p1;
    #pragma unroll
    for (int off = 32; off >= 1; off >>= 1) {
      t0 += __shfl_xor(t0, off, 64);
      if (H == 2) t1 += __shfl_xor(t1, off, 64);
    }
    s0 += t0; if (H == 2) s1 += t1;

    // gather: 1 edge per step, all 64 lanes (8B each), 4 edges in flight.
    // Padded edges (e >= cnt) have src=0, p=0 -> weight-0 row-0 loads (harmless).
    int ne4 = (cnt + 3) & ~3;
    for (int e = 0; e < ne4; e += 4) {
      ushort4 v[4]; float aw[4];
      #pragma unroll
      for (int u = 0; u < 4; ++u) {
        int sidx = __builtin_amdgcn_readlane(src_i, e + u);      // SGPR
        float a0 = bcastf(p0, e + u);
        if (H == 2) {
          float a1 = bcastf(p1, e + u);
          aw[u] = head ? a1 : a0;
        } else {
          aw[u] = a0;
        }
        v[u] = *(const ushort4*)&hin[(size_t)sidx * 256 + lane * 4];
      }
      #pragma unroll
      for (int u = 0; u < 4; ++u) {
        acc[0] = fmaf(bf2f(v[u].x), aw[u], acc[0]);
        acc[1] = fmaf(bf2f(v[u].y), aw[u], acc[1]);
        acc[2] = fmaf(bf2f(v[u].z), aw[u], acc[2]);
        acc[3] = fmaf(bf2f(v[u].w), aw[u], acc[3]);
      }
    }
  }

  float sh = (H == 2 && head) ? s1 : s0;
  float inv = 1.0f / sh;
  float4 bv = *(const float4*)&bias[lane * 4];
  float o0 = acc[0] * inv + bv.x, o1 = acc[1] * inv + bv.y;
  float o2 = acc[2] * inv + bv.z, o3 = acc[3] * inv + bv.w;
  if (OUT_LRELU) {
    o0 = lrelu(o0, 0.01f); o1 = lrelu(o1, 0.01f);
    o2 = lrelu(o2, 0.01f); o3 = lrelu(o3, 0.01f);
  }
  ushort4 o;
  o.x = f2bf(o0); o.y = f2bf(o1); o.z = f2bf(o2); o.w = f2bf(o3);
  *(ushort4*)&outp[(size_t)n * 256 + lane * 4] = o;
}

// ======================== mu norms ========================
__global__ __launch_bounds__(64) void munorm_kernel(const float* __restrict__ mu,
                                                    float* __restrict__ norm_mu) {
  int lane = threadIdx.x;
  for (int k = 0; k < 8; ++k) {
    float v0 = mu[k * 128 + lane];
    float v1 = mu[k * 128 + 64 + lane];
    float s = v0 * v0 + v1 * v1;
    #pragma unroll
    for (int off = 1; off < 64; off <<= 1) s += __shfl_xor(s, off, 64);
    if (lane == 0) norm_mu[k] = sqrtf(s);
  }
}

// ======================== launch ========================
extern "C" void kernel_launch(void* const* d_in, const int* in_sizes, int n_in,
                              void* d_out, int out_size, void* d_ws, size_t ws_size,
                              hipStream_t stream) {
  const float* x      = (const float*)d_in[0];
  const int*   ei     = (const int*)  d_in[1];
  const float* W1     = (const float*)d_in[2];
  const float* a_src1 = (const float*)d_in[3];
  const float* a_dst1 = (const float*)d_in[4];
  const float* b1     = (const float*)d_in[5];
  const float* W2     = (const float*)d_in[6];
  const float* a_src2 = (const float*)d_in[7];
  const float* a_dst2 = (const float*)d_in[8];
  const float* b2     = (const float*)d_in[9];
  const float* g      = (const float*)d_in[10];
  const float* mu     = (const float*)d_in[11];

  const int N  = in_sizes[0] / 256;            // 50000
  const int E  = in_sizes[1] / 2;              // 800000
  const int Mp = ((N + 127) / 128) * 128;      // 50048
  const int nb = (N + 255) / 256;              // 196 scan blocks
  const int* src = ei;
  const int* dst = ei + E;

  // ---- workspace layout ----
  unsigned short* us = (unsigned short*)d_ws;
  size_t off = 0;
  unsigned short* xb  = us + off; off += (size_t)Mp * 256;   // x bf16 (reused as out2b)
  unsigned short* h1b = us + off; off += (size_t)Mp * 256;
  unsigned short* o1b = us + off; off += (size_t)Mp * 256;
  unsigned short* h2b = us + off; off += (size_t)Mp * 256;
  unsigned short* o2b = xb;                                  // alias: xb dead after gemm1
  float* f = (float*)(us + off);
  size_t fo = 0;
  float* asrc1 = f + fo; fo += (size_t)N * 2;
  float* adst1 = f + fo; fo += (size_t)N * 2;
  float* asrc2 = f + fo; fo += N;
  float* adst2 = f + fo; fo += N;
  float* nmu   = f + fo; fo += 8;
  int* deg    = (int*)(f + fo);
  int* rowptr = deg + N;
  int* cursor = rowptr + N + 1;
  int* colsrc = cursor + N;
  int* bsum   = colsrc + E;          // nb
  int* boff   = bsum + 256;          // nb
  unsigned short* w1b = (unsigned short*)(boff + 256);
  unsigned short* w2b = w1b + 256 * 256;
  unsigned short* gTb = w2b + 256 * 256;

  // ---- CSR build ----
  hipMemsetAsync(deg, 0, (size_t)N * sizeof(int), stream);
  hipMemsetAsync(asrc2, 0, (size_t)N * 2 * sizeof(float), stream);  // asrc2+adst2 contiguous
  deg_kernel<<<(E + 255) / 256, 256, 0, stream>>>(dst, deg, E);
  bsum_kernel<<<nb, 256, 0, stream>>>(deg, bsum, N);
  bscan_kernel<<<1, 256, 0, stream>>>(bsum, boff, nb, rowptr + N);
  bwrite_kernel<<<nb, 256, 0, stream>>>(deg, boff, rowptr, cursor, N);
  fill_kernel<<<(E + 255) / 256, 256, 0, stream>>>(src, dst, cursor, colsrc, E);

  // ---- conversions ----
  cvt_rows_kernel<<<Mp / 4, 256, 0, stream>>>(x, xb, N, Mp);
  cvt_rows_kernel<<<64, 256, 0, stream>>>(W1, w1b, 256, 256);
  cvt_rows_kernel<<<64, 256, 0, stream>>>(W2, w2b, 256, 256);
  cvt_gT_kernel<<<1024, 256, 0, stream>>>(g, gTb);
  munorm_kernel<<<1, 64, 0, stream>>>(mu, nmu);

  const int gm = Mp / 128;   // 391

  // ---- layer 1 (alpha fused into GEMM epilogue: blockIdx.y == head) ----
  gemm_bf16<0, 2><<<dim3(gm, 2), 256, 0, stream>>>(xb, w1b, h1b,
      a_src1, a_dst1, asrc1, adst1, nullptr, nullptr, nullptr, N);
  agg_kernel<2, true><<<(N + 3) / 4, 256, 0, stream>>>(h1b, asrc1, adst1, rowptr, colsrc, b1, o1b, N);

  // ---- layer 2 (alpha partials via atomicAdd into zeroed asrc2/adst2) ----
  gemm_bf16<0, 1><<<dim3(gm, 2), 256, 0, stream>>>(o1b, w2b, h2b,
      a_src2, a_dst2, asrc2, adst2, nullptr, nullptr, nullptr, N);
  agg_kernel<1, false><<<(N + 3) / 4, 256, 0, stream>>>(h2b, asrc2, adst2, rowptr, colsrc, b2, o2b, N);

  // ---- projection + fused cosine ----
  gemm_bf16<1, 0><<<dim3(gm, 8), 256, 0, stream>>>(o2b, gTb, nullptr,
      nullptr, nullptr, nullptr, nullptr, mu, nmu, (float*)d_out, N);
}